// Round 1
// baseline (126.575 us; speedup 1.0000x reference)
//
#include <hip/hip_runtime.h>
#include <stdint.h>

typedef __attribute__((ext_vector_type(8))) short bf16x8v;   // 8 bf16 (4 VGPRs)
typedef __attribute__((ext_vector_type(4))) float f32x4v;    // 4 fp32 acc

#define MFMA16(a,b,c) __builtin_amdgcn_mfma_f32_16x16x32_bf16((a),(b),(c),0,0,0)

__device__ __forceinline__ unsigned short f2b(float f){   // f32 -> bf16 RNE
  union { float f; unsigned int u; } v; v.f = f;
  unsigned int u = v.u;
  return (unsigned short)((u + 0x7FFFu + ((u >> 16) & 1u)) >> 16);
}
__device__ __forceinline__ float b2f(unsigned int lo16){  // low 16 bits = bf16
  union { unsigned int u; float f; } v; v.u = lo16 << 16;
  return v.f;
}

// ---------------------------------------------------------------------------
// Pack w1a^T / w1b^T / w2^T into MFMA A-fragment order:
//   pk[mat][ks][mt][lane][j] = W[i = ks*32 + (lane>>4)*8 + j][c = mt*16 + (lane&15)]
// so an A-fragment is ONE coalesced 16B load.
__global__ void __launch_bounds__(256) k_prep(const float* __restrict__ w1,
                                              const float* __restrict__ w2,
                                              unsigned short* __restrict__ pk){
  int tid = blockIdx.x*256 + threadIdx.x;
  if (tid >= 3*2048) return;
  int mat = tid >> 11;
  int rem = tid & 2047;
  int ks = rem >> 9;
  int mt = (rem >> 6) & 7;
  int l  = rem & 63;
  int kb = ks*32 + ((l>>4)<<3);
  int c  = mt*16 + (l&15);
  const float* src = (mat==0) ? w1 : (mat==1) ? (w1 + 128*128) : w2;
  bf16x8v v;
  #pragma unroll
  for(int j=0;j<8;j++) v[j] = (short)f2b(src[(size_t)(kb+j)*128 + c]);
  *reinterpret_cast<bf16x8v*>(pk + ((size_t)mat*2048 + (ks*8+mt)*64 + l)*8) = v;
}

// user_emb (f32) -> bf16 table
__global__ void __launch_bounds__(256) k_conv(const float* __restrict__ emb,
                                              unsigned short* __restrict__ tab,
                                              long long total){
  long long i = ((long long)blockIdx.x*256 + threadIdx.x)*4;
  if (i >= total) return;
  float4 f = *reinterpret_cast<const float4*>(emb + i);
  uint2 w;
  w.x = (unsigned int)f2b(f.x) | ((unsigned int)f2b(f.y)<<16);
  w.y = (unsigned int)f2b(f.z) | ((unsigned int)f2b(f.w)<<16);
  *reinterpret_cast<uint2*>(tab + i) = w;
}

// p1[n][c1] = sum_i parent_n[i]*w1[128+i][c1] + b1[c1]   (16 nodes per 1-wave block)
template<bool TBF>
__global__ void __launch_bounds__(64) k_parent(const int* __restrict__ nodes,
                                               const unsigned short* __restrict__ tab,
                                               const float* __restrict__ emb,
                                               const unsigned short* __restrict__ w1bpk,
                                               const float* __restrict__ b1,
                                               float* __restrict__ p1, int N){
  __shared__ __align__(16) unsigned short par[16*128];
  const int l = threadIdx.x;
  const int base = blockIdx.x*16;
  const int nn = (base + 16 <= N) ? 16 : (N - base);
  #pragma unroll
  for(int r=0;r<16;r++){
    unsigned int w = 0;
    if (r < nn){
      int idx = nodes[base + r];
      if (TBF){
        w = *reinterpret_cast<const unsigned int*>(tab + (size_t)idx*128 + l*2);
      } else {
        const float* s = emb + (size_t)idx*128 + l*2;
        w = (unsigned int)f2b(s[0]) | ((unsigned int)f2b(s[1])<<16);
      }
    }
    const int cb = (l*4) ^ ((r&7)<<4);
    *reinterpret_cast<unsigned int*>(reinterpret_cast<char*>(par) + r*256 + cb) = w;
  }
  __syncthreads();
  f32x4v acc[8];
  #pragma unroll
  for(int mt=0;mt<8;mt++)
    acc[mt] = *reinterpret_cast<const f32x4v*>(b1 + mt*16 + ((l>>4)<<2));
  const int rr = l & 15;
  #pragma unroll
  for(int ks=0;ks<4;ks++){
    const int cb = (ks*64 + ((l>>4)<<4)) ^ ((rr&7)<<4);
    bf16x8v bf = *reinterpret_cast<const bf16x8v*>(reinterpret_cast<const char*>(par) + rr*256 + cb);
    #pragma unroll
    for(int mt=0;mt<8;mt++){
      bf16x8v af = *reinterpret_cast<const bf16x8v*>(w1bpk + ((size_t)((ks*8+mt)*64 + l))*8);
      acc[mt] = MFMA16(af, bf, acc[mt]);
    }
  }
  if (rr < nn){
    const size_t node = base + rr;
    #pragma unroll
    for(int mt=0;mt<8;mt++)
      *reinterpret_cast<f32x4v*>(p1 + node*128 + mt*16 + ((l>>4)<<2)) = acc[mt];
  }
}

// One wave = one node. Swapped GEMMs: D1[c1][r] = w1a^T @ neigh^T (+p1),
// D2[c2][r] = w2^T @ h1^T (+b2); score/softmax in-register; VALU weighted sum.
template<bool TBF>
__global__ void __launch_bounds__(64) k_main(const int* __restrict__ neighbours,
                                             const unsigned short* __restrict__ tab,
                                             const float* __restrict__ emb,
                                             const unsigned short* __restrict__ w1apk,
                                             const unsigned short* __restrict__ w2pk,
                                             const float* __restrict__ p1,
                                             const float* __restrict__ b2,
                                             const float* __restrict__ w3,
                                             float* __restrict__ out){
  __shared__ __align__(16) unsigned short ngh[32*128];  // 8 KB, XOR-swizzled rows
  __shared__ __align__(16) unsigned short h1s[32*128];  // 8 KB
  const int l = threadIdx.x;
  const int n = blockIdx.x;
  const int lh = l & 31;
  const int rh = l >> 5;
  // ---- gather 32 neighbor rows into swizzled bf16 LDS (2 rows / iter)
  #pragma unroll
  for(int rr=0; rr<32; rr+=2){
    const int r = rr + rh;
    const int idx = neighbours[n*32 + r];
    uint2 w;
    if (TBF){
      w = *reinterpret_cast<const uint2*>(tab + (size_t)idx*128 + lh*4);
    } else {
      float4 f = *reinterpret_cast<const float4*>(emb + (size_t)idx*128 + lh*4);
      w.x = (unsigned int)f2b(f.x) | ((unsigned int)f2b(f.y)<<16);
      w.y = (unsigned int)f2b(f.z) | ((unsigned int)f2b(f.w)<<16);
    }
    const int cb = (lh*8) ^ ((r&7)<<4);
    *reinterpret_cast<uint2*>(reinterpret_cast<char*>(ngh) + r*256 + cb) = w;
  }
  __syncthreads();
  const int g4 = (l>>4)<<2;
  const int r0 = l & 15, r1 = r0 + 16;
  // ---- layer 1 (acc init = p1 row: parent term + b1 pre-folded)
  f32x4v acc[8][2];
  #pragma unroll
  for(int mt=0;mt<8;mt++){
    f32x4v pv = *reinterpret_cast<const f32x4v*>(p1 + (size_t)n*128 + mt*16 + g4);
    acc[mt][0] = pv; acc[mt][1] = pv;
  }
  #pragma unroll
  for(int ks=0;ks<4;ks++){
    const int cbase = ks*64 + ((l>>4)<<4);
    bf16x8v nb0 = *reinterpret_cast<const bf16x8v*>(reinterpret_cast<const char*>(ngh) + r0*256 + (cbase ^ ((r0&7)<<4)));
    bf16x8v nb1 = *reinterpret_cast<const bf16x8v*>(reinterpret_cast<const char*>(ngh) + r1*256 + (cbase ^ ((r1&7)<<4)));
    #pragma unroll
    for(int mt=0;mt<8;mt++){
      bf16x8v af = *reinterpret_cast<const bf16x8v*>(w1apk + ((size_t)((ks*8+mt)*64 + l))*8);
      acc[mt][0] = MFMA16(af, nb0, acc[mt][0]);
      acc[mt][1] = MFMA16(af, nb1, acc[mt][1]);
    }
  }
  // ---- relu -> bf16 -> h1 LDS (rows = neighbor index, 8B contiguous writes)
  #pragma unroll
  for(int mt=0;mt<8;mt++){
    #pragma unroll
    for(int nt=0;nt<2;nt++){
      const int r = nt*16 + r0;
      uint2 w;
      w.x = (unsigned int)f2b(fmaxf(acc[mt][nt][0],0.f)) | ((unsigned int)f2b(fmaxf(acc[mt][nt][1],0.f))<<16);
      w.y = (unsigned int)f2b(fmaxf(acc[mt][nt][2],0.f)) | ((unsigned int)f2b(fmaxf(acc[mt][nt][3],0.f))<<16);
      const int cb = (mt*32 + ((l>>4)<<3)) ^ ((r&7)<<4);
      *reinterpret_cast<uint2*>(reinterpret_cast<char*>(h1s) + r*256 + cb) = w;
    }
  }
  __syncthreads();
  // ---- layer 2 (acc init = b2)
  f32x4v acc2[8][2];
  #pragma unroll
  for(int mt=0;mt<8;mt++){
    f32x4v bv = *reinterpret_cast<const f32x4v*>(b2 + mt*16 + g4);
    acc2[mt][0] = bv; acc2[mt][1] = bv;
  }
  #pragma unroll
  for(int ks=0;ks<4;ks++){
    const int cbase = ks*64 + ((l>>4)<<4);
    bf16x8v hb0 = *reinterpret_cast<const bf16x8v*>(reinterpret_cast<const char*>(h1s) + r0*256 + (cbase ^ ((r0&7)<<4)));
    bf16x8v hb1 = *reinterpret_cast<const bf16x8v*>(reinterpret_cast<const char*>(h1s) + r1*256 + (cbase ^ ((r1&7)<<4)));
    #pragma unroll
    for(int mt=0;mt<8;mt++){
      bf16x8v af = *reinterpret_cast<const bf16x8v*>(w2pk + ((size_t)((ks*8+mt)*64 + l))*8);
      acc2[mt][0] = MFMA16(af, hb0, acc2[mt][0]);
      acc2[mt][1] = MFMA16(af, hb1, acc2[mt][1]);
    }
  }
  // ---- scores: s[r] = sum_c2 relu(h2[r][c2]) * w3[c2]   (b3 is softmax-invariant)
  float s0 = 0.f, s1 = 0.f;
  #pragma unroll
  for(int mt=0;mt<8;mt++){
    f32x4v w3v = *reinterpret_cast<const f32x4v*>(w3 + mt*16 + g4);
    #pragma unroll
    for(int j=0;j<4;j++){
      s0 += fmaxf(acc2[mt][0][j],0.f) * w3v[j];
      s1 += fmaxf(acc2[mt][1][j],0.f) * w3v[j];
    }
  }
  s0 += __shfl_xor(s0, 16); s0 += __shfl_xor(s0, 32);
  s1 += __shfl_xor(s1, 16); s1 += __shfl_xor(s1, 32);
  // ---- softmax over 32 neighbors (scores r0 -> s0, r0+16 -> s1)
  float m = fmaxf(s0, s1);
  #pragma unroll
  for(int d=1; d<16; d<<=1) m = fmaxf(m, __shfl_xor(m, d));
  const float e0 = __expf(s0 - m), e1 = __expf(s1 - m);
  float sum = e0 + e1;
  #pragma unroll
  for(int d=1; d<16; d<<=1) sum += __shfl_xor(sum, d);
  const float inv = 1.f / sum;
  const float a0 = e0*inv, a1 = e1*inv;
  // ---- weighted sum: out[c] = sum_r attn[r]*neigh[r][c]; lane owns cols 2l,2l+1
  float o0 = 0.f, o1 = 0.f;
  #pragma unroll
  for(int r=0;r<32;r++){
    const float ar = __shfl((r<16) ? a0 : a1, r & 15);
    const unsigned int u = *reinterpret_cast<const unsigned int*>(
        reinterpret_cast<const char*>(ngh) + r*256 + ((l*4) ^ ((r&7)<<4)));
    o0 += ar * b2f(u & 0xffffu);
    o1 += ar * b2f(u >> 16);
  }
  *reinterpret_cast<float2*>(out + (size_t)n*128 + l*2) = make_float2(o0, o1);
}

extern "C" void kernel_launch(void* const* d_in, const int* in_sizes, int n_in,
                              void* d_out, int out_size, void* d_ws, size_t ws_size,
                              hipStream_t stream){
  const int*   nodes = (const int*)d_in[0];
  const int*   neigh = (const int*)d_in[1];
  const float* emb   = (const float*)d_in[2];
  const float* w1    = (const float*)d_in[3];
  const float* b1    = (const float*)d_in[4];
  const float* w2    = (const float*)d_in[5];
  const float* b2    = (const float*)d_in[6];
  const float* w3    = (const float*)d_in[7];
  float* out = (float*)d_out;

  const int N = in_sizes[0];                 // 20000
  const long long embElems = in_sizes[2];    // 100000*128
  char* ws = (char*)d_ws;
  unsigned short* pk  = (unsigned short*)ws;               // 3*16384 u16 = 98304 B
  float*          p1  = (float*)(ws + 98304);              // N*128 f32
  size_t off_tab = 98304 + (size_t)N*512;
  off_tab = (off_tab + 255) & ~(size_t)255;
  unsigned short* tab = (unsigned short*)(ws + off_tab);
  const bool use_tab = ws_size >= off_tab + (size_t)embElems*2;

  k_prep<<<24, 256, 0, stream>>>(w1, w2, pk);
  const int pblocks = (N + 15) / 16;
  if (use_tab){
    const int cblocks = (int)((embElems/4 + 255) / 256);
    k_conv<<<cblocks, 256, 0, stream>>>(emb, tab, embElems);
    k_parent<true><<<pblocks, 64, 0, stream>>>(nodes, tab, emb, pk + 16384, b1, p1, N);
    k_main<true><<<N, 64, 0, stream>>>(neigh, tab, emb, pk, pk + 32768, p1, b2, w3, out);
  } else {
    k_parent<false><<<pblocks, 64, 0, stream>>>(nodes, tab, emb, pk + 16384, b1, p1, N);
    k_main<false><<<N, 64, 0, stream>>>(neigh, tab, emb, pk, pk + 32768, p1, b2, w3, out);
  }
}